// Round 13
// baseline (199.561 us; speedup 1.0000x reference)
//
#include <hip/hip_runtime.h>
#include <hip/hip_bf16.h>
#include <stdint.h>

#define N_SRC_C 100000
#define N_DST_C 100000
#define M_TOT   200000
#define E_C     1600000
#define IN_FC   256
#define HEADS_C 8
#define OUT_FC  32
#define HF_C    256
#define HPITCH  288                  // Hx row: 256 h | 8 k | 24 pad (576 B)

// GEMM tile geometry
#define BMg 128
#define BKg 32
#define BPITCH 40                    // LDS row pitch in elems (32 + 8 pad, 80B = 2-way max)
#define A_ELEMS (BMg * BPITCH)       // 5120 elems / buffer
#define B_ROWS 272
#define B_ELEMS (B_ROWS * BPITCH)    // 10880 elems / buffer (21760 B)
#define B_CHUNKS 1360                // 21760 B / 16

typedef float f32x4_t __attribute__((ext_vector_type(4)));
typedef short s16x8_t __attribute__((ext_vector_type(8)));

static __device__ __forceinline__ unsigned short f2bf(float f) {
    union { __hip_bfloat16 h; unsigned short u; } cv;
    cv.h = __float2bfloat16(f);
    return cv.u;
}
static __device__ __forceinline__ float bf2f(unsigned short u) {
    return __uint_as_float(((unsigned int)u) << 16);
}

static __device__ __forceinline__ s16x8_t cvt8(f32x4_t x0, f32x4_t x1) {
    union { s16x8_t v; unsigned short u[8]; } r;
    r.u[0] = f2bf(x0[0]); r.u[1] = f2bf(x0[1]);
    r.u[2] = f2bf(x0[2]); r.u[3] = f2bf(x0[3]);
    r.u[4] = f2bf(x1[0]); r.u[5] = f2bf(x1[1]);
    r.u[6] = f2bf(x1[2]); r.u[7] = f2bf(x1[3]);
    return r.v;
}

// ---------------- K0: fused prep ----------------
__global__ __launch_bounds__(256) void k_prep(
    const float* __restrict__ Wv, const float* __restrict__ bv,
    const float* __restrict__ Wq, const float* __restrict__ bq,
    const float* __restrict__ Wk, const float* __restrict__ bk,
    const int* __restrict__ dst_idx,
    unsigned short* __restrict__ WTpad, float* __restrict__ baux16,
    int* __restrict__ off) {
    const int b = blockIdx.x;
    const int tid = threadIdx.x;
    __shared__ float sq[4][8], sk[4][8];
    if (b < 257) {
        const int i = b;
        float vv = (i < 256) ? Wv[(size_t)i * HF_C + tid] : bv[tid];
        f32x4_t q0 = *(const f32x4_t*)(Wq + tid * 8);
        f32x4_t q1 = *(const f32x4_t*)(Wq + tid * 8 + 4);
        f32x4_t k0 = *(const f32x4_t*)(Wk + tid * 8);
        f32x4_t k1 = *(const f32x4_t*)(Wk + tid * 8 + 4);
        float pq[8], pk[8];
#pragma unroll
        for (int h = 0; h < 4; ++h) {
            pq[h] = vv * q0[h]; pq[4 + h] = vv * q1[h];
            pk[h] = vv * k0[h]; pk[4 + h] = vv * k1[h];
        }
#pragma unroll
        for (int m = 1; m < 64; m <<= 1) {
#pragma unroll
            for (int h = 0; h < 8; ++h) {
                pq[h] += __shfl_xor(pq[h], m);
                pk[h] += __shfl_xor(pk[h], m);
            }
        }
        const int w = tid >> 6, ln = tid & 63;
        if (ln == 0) {
#pragma unroll
            for (int h = 0; h < 8; ++h) { sq[w][h] = pq[h]; sk[w][h] = pk[h]; }
        }
        __syncthreads();
        if (tid < 8) {
            float fq = sq[0][tid] + sq[1][tid] + sq[2][tid] + sq[3][tid];
            float fk = sk[0][tid] + sk[1][tid] + sk[2][tid] + sk[3][tid];
            if (i < 256) {
                WTpad[(i >> 5) * B_ELEMS + (256 + tid) * BPITCH + (i & 31)] = f2bf(fk);
                WTpad[(i >> 5) * B_ELEMS + (264 + tid) * BPITCH + (i & 31)] = f2bf(fq);
            } else {
                baux16[tid]     = fk + bk[tid];
                baux16[8 + tid] = fq + bq[tid];
            }
        }
        if (i < 256)
            WTpad[(tid >> 5) * B_ELEMS + i * BPITCH + (tid & 31)] =
                f2bf(Wv[(size_t)tid * HF_C + i]);
    } else {
        int n = (b - 257) * 256 + tid;
        if (n > N_DST_C) return;
        if (n == N_DST_C) { off[n] = E_C; return; }
        int lo = 0, hi = E_C;
        while (lo < hi) {
            int mid = (lo + hi) >> 1;
            if (dst_idx[mid] < n) lo = mid + 1; else hi = mid;
        }
        off[n] = lo;
    }
}

// ---------------- K1: pipelined merged GEMM over [x_src; x_dst] ----------------
// src rows -> Hx row (256 h bf16 + 8 k bf16, pitch 288); dst rows -> q(f32)
__global__ __launch_bounds__(512, 4) void k_gemm(
    const float* __restrict__ Xs, const float* __restrict__ Xd,
    const unsigned short* __restrict__ WTpad,
    const float* __restrict__ bmain, const float* __restrict__ baux16,
    unsigned short* __restrict__ Hx, float* __restrict__ qo) {
    __shared__ unsigned short smem[2 * A_ELEMS + 2 * B_ELEMS];   // 64,000 B
    unsigned short* As = smem;
    unsigned short* Bs = smem + 2 * A_ELEMS;
    const int tid  = threadIdx.x;
    const int lane = tid & 63;
    const int w    = tid >> 6;
    const int wr   = w >> 2, wc = w & 3;
    const int row0 = blockIdx.x * BMg;
    const bool need_main = (row0 < N_SRC_C);

    const int ar = tid >> 2, acg = tid & 3;
    int gr = row0 + ar; if (gr >= M_TOT) gr = M_TOT - 1;
    const float* arow = (gr < N_SRC_C) ? (Xs + (size_t)gr * IN_FC)
                                       : (Xd + (size_t)(gr - N_SRC_C) * IN_FC);

#define STAGE_B(kt, buf)                                                          \
    {                                                                             \
        const unsigned short* gsrc = WTpad + (size_t)(kt) * B_ELEMS;              \
        unsigned short* ldst = Bs + (buf) * B_ELEMS;                              \
        for (int g = w; g < 22; g += 8) {                                         \
            int c = g * 64 + lane;                                                \
            if (c < B_CHUNKS) {                                                   \
                __builtin_amdgcn_global_load_lds(                                 \
                    (const __attribute__((address_space(1))) unsigned int*)(gsrc + (size_t)c * 8), \
                    (__attribute__((address_space(3))) unsigned int*)(ldst + (size_t)c * 8),       \
                    16, 0, 0);                                                    \
            }                                                                     \
        }                                                                         \
    }

    f32x4_t acc[4][4];
    f32x4_t accA = {0.f, 0.f, 0.f, 0.f};
    const f32x4_t z = {0.f, 0.f, 0.f, 0.f};
#pragma unroll
    for (int m = 0; m < 4; ++m)
#pragma unroll
        for (int n = 0; n < 4; ++n) acc[m][n] = z;

    f32x4_t a0 = *(const f32x4_t*)(arow + acg * 8);
    f32x4_t a1 = *(const f32x4_t*)(arow + acg * 8 + 4);
    STAGE_B(0, 0);
    *(s16x8_t*)(As + ar * BPITCH + acg * 8) = cvt8(a0, a1);
    __syncthreads();
    a0 = *(const f32x4_t*)(arow + 32 + acg * 8);
    a1 = *(const f32x4_t*)(arow + 32 + acg * 8 + 4);
    STAGE_B(1, 1);

    const int koff = (lane >> 4) * 8;
    const int fr   = lane & 15;

    for (int kt = 0; kt < 8; ++kt) {
        const int cur = kt & 1;
        const unsigned short* Ab = As + cur * A_ELEMS;
        const unsigned short* Bb = Bs + cur * B_ELEMS;
        s16x8_t aa = *(const s16x8_t*)(Ab + (w * 16 + fr) * BPITCH + koff);
        s16x8_t ba = *(const s16x8_t*)(Bb + (256 + fr) * BPITCH + koff);
        accA = __builtin_amdgcn_mfma_f32_16x16x32_bf16(aa, ba, accA, 0, 0, 0);
        if (need_main) {
            s16x8_t a[4];
#pragma unroll
            for (int m = 0; m < 4; ++m)
                a[m] = *(const s16x8_t*)(Ab + (wr * 64 + m * 16 + fr) * BPITCH + koff);
#pragma unroll
            for (int n = 0; n < 4; ++n) {
                s16x8_t bf = *(const s16x8_t*)(Bb + (wc * 64 + n * 16 + fr) * BPITCH + koff);
#pragma unroll
                for (int m = 0; m < 4; ++m)
                    acc[m][n] = __builtin_amdgcn_mfma_f32_16x16x32_bf16(a[m], bf, acc[m][n], 0, 0, 0);
            }
        }
        if (kt < 7) {
            *(s16x8_t*)(As + (cur ^ 1) * A_ELEMS + ar * BPITCH + acg * 8) = cvt8(a0, a1);
            __syncthreads();
            if (kt < 6) {
                a0 = *(const f32x4_t*)(arow + (kt + 2) * 32 + acg * 8);
                a1 = *(const f32x4_t*)(arow + (kt + 2) * 32 + acg * 8 + 4);
                STAGE_B(kt + 2, cur);
            }
        }
    }

    // aux epilogue: k -> Hx tail (src rows), q -> qo (dst rows)
    {
        const int col0 = lane & 15;
        const float bb = baux16[col0];
        const int rb = row0 + w * 16 + (lane >> 4) * 4;
#pragma unroll
        for (int j = 0; j < 4; ++j) {
            int r = rb + j;
            float v = accA[j] + bb;
            if (r < N_SRC_C) {
                if (col0 < 8) Hx[(size_t)r * HPITCH + 256 + col0] = f2bf(v);
            } else if (r < M_TOT) {
                if (col0 >= 8) qo[(size_t)(r - N_SRC_C) * 8 + (col0 - 8)] = v;
            }
        }
    }

    // main epilogue: per-wave LDS repack (pitch 72, conflict-free) -> 16B Hx stores
    if (need_main) {
        __syncthreads();
        unsigned short* reg = smem + w * 2304;   // 32 rows x 72
        float bb[4];
#pragma unroll
        for (int n = 0; n < 4; ++n) bb[n] = bmain[wc * 64 + n * 16 + fr];
#pragma unroll
        for (int g2 = 0; g2 < 2; ++g2) {
#pragma unroll
            for (int m2 = 0; m2 < 2; ++m2)
#pragma unroll
                for (int n = 0; n < 4; ++n)
#pragma unroll
                    for (int j = 0; j < 4; ++j) {
                        int lr = m2 * 16 + (lane >> 4) * 4 + j;
                        reg[lr * 72 + n * 16 + fr] = f2bf(acc[g2 * 2 + m2][n][j] + bb[n]);
                    }
#pragma unroll
            for (int i = 0; i < 4; ++i) {
                int lr = i * 8 + (lane >> 3);
                s16x8_t v = *(const s16x8_t*)(reg + lr * 72 + (lane & 7) * 8);
                int grr = row0 + wr * 64 + g2 * 32 + lr;
                if (grr < N_SRC_C)
                    *(s16x8_t*)(Hx + (size_t)grr * HPITCH + wc * 64 + (lane & 7) * 8) = v;
            }
            __syncthreads();
        }
    }
#undef STAGE_B
}

// ---------------- K2: fused weights (k embedded in Hx rows) + aggregation ----------------
// weight/den layout: lane = 8*e_sub + h_w   (8 edge-slots x 8 heads)
// gather layout:     lane = 32*ep + 4*hh + fc2  (2 edge-slots x 8 heads x 4 chunks of 8)
__global__ __launch_bounds__(256) void k_gat_agg(
    const int* __restrict__ src_idx, const int* __restrict__ off,
    const float* __restrict__ q, const unsigned short* __restrict__ Hx,
    float* __restrict__ outp) {
    const int wv = (blockIdx.x * 256 + threadIdx.x) >> 6;
    const int lane = threadIdx.x & 63;
    if (wv >= N_DST_C) return;
    const int o0 = off[wv], o1 = off[wv + 1];
    const int e_sub = lane >> 3;
    const int h_w   = lane & 7;
    const int hh    = (lane >> 2) & 7;
    const int fc2   = lane & 3;
    const int selA  = ((lane >> 5) << 3) | hh;   // 8*ep + hh
    if (o1 <= o0) {
        if (lane < 4) {
            f32x4_t zv = {0.f, 0.f, 0.f, 0.f};
            *(f32x4_t*)(outp + (size_t)wv * 32 + lane * 8) = zv;
            *(f32x4_t*)(outp + (size_t)wv * 32 + lane * 8 + 4) = zv;
        }
        return;
    }
    const int last = o1 - 1;
    const float q_w = q[(size_t)wv * 8 + h_w];
    float den_w = 0.f;
    float a[8];
#pragma unroll
    for (int i = 0; i < 8; ++i) a[i] = 0.f;
    const unsigned short* Hb = Hx + hh * 32 + fc2 * 8;

    int s0 = src_idx[min(o0 + e_sub, last)];
    int s1 = src_idx[min(o0 + 8 + e_sub, last)];

    for (int base = o0; base < o1; base += 16) {
        // 1) issue all 8 row-gathers (depend only on s0/s1)
        uint4 xv[8];
#pragma unroll
        for (int j = 0; j < 4; ++j) {
            const int se = __shfl(s0, j * 16 + selA);
            xv[j] = *(const uint4*)(Hb + (size_t)se * HPITCH);
        }
#pragma unroll
        for (int j = 0; j < 4; ++j) {
            const int se = __shfl(s1, j * 16 + selA);
            xv[4 + j] = *(const uint4*)(Hb + (size_t)se * HPITCH);
        }
        // 2) weights from the embedded k-tail (same cached region as the rows)
        const float kv0 = bf2f(Hx[(size_t)s0 * HPITCH + 256 + h_w]);
        const float kv1 = bf2f(Hx[(size_t)s1 * HPITCH + 256 + h_w]);
        // 3) prefetch next tile indices
        const int sn0 = src_idx[min(base + 16 + e_sub, last)];
        const int sn1 = src_idx[min(base + 24 + e_sub, last)];
        float ev0 = q_w + kv0; ev0 = (ev0 >= 0.f) ? ev0 : 0.2f * ev0;
        float ev1 = q_w + kv1; ev1 = (ev1 >= 0.f) ? ev1 : 0.2f * ev1;
        const float p0 = (base + e_sub < o1) ? __expf(ev0) : 0.f;
        const float p1 = (base + 8 + e_sub < o1) ? __expf(ev1) : 0.f;
        den_w += p0 + p1;
#pragma unroll
        for (int j = 0; j < 8; ++j) {
            const float wgt = __shfl(j < 4 ? p0 : p1, (j & 3) * 16 + selA);
            a[0] += wgt * __uint_as_float(xv[j].x << 16);
            a[1] += wgt * __uint_as_float(xv[j].x & 0xffff0000u);
            a[2] += wgt * __uint_as_float(xv[j].y << 16);
            a[3] += wgt * __uint_as_float(xv[j].y & 0xffff0000u);
            a[4] += wgt * __uint_as_float(xv[j].z << 16);
            a[5] += wgt * __uint_as_float(xv[j].z & 0xffff0000u);
            a[6] += wgt * __uint_as_float(xv[j].w << 16);
            a[7] += wgt * __uint_as_float(xv[j].w & 0xffff0000u);
        }
        s0 = sn0; s1 = sn1;
    }
    // denominator: reduce over edge-slot lanes (weight layout)
    den_w += __shfl_xor(den_w, 8);
    den_w += __shfl_xor(den_w, 16);
    den_w += __shfl_xor(den_w, 32);
    const float rs_w = 1.f / (den_w + 1e-9f);
    const float rs_a = __shfl(rs_w, hh) * 0.125f;   // per-head norm + /8 head-mean
#pragma unroll
    for (int i = 0; i < 8; ++i) {
        a[i] += __shfl_xor(a[i], 32);   // sum the two edge-slot halves
        a[i] *= rs_a;
        a[i] += __shfl_xor(a[i], 4);    // sum over heads (bits 2..4)
        a[i] += __shfl_xor(a[i], 8);
        a[i] += __shfl_xor(a[i], 16);
    }
    if (lane < 4) {
        f32x4_t v0 = {a[0], a[1], a[2], a[3]};
        f32x4_t v1 = {a[4], a[5], a[6], a[7]};
        *(f32x4_t*)(outp + (size_t)wv * 32 + lane * 8) = v0;
        *(f32x4_t*)(outp + (size_t)wv * 32 + lane * 8 + 4) = v1;
    }
}

extern "C" void kernel_launch(void* const* d_in, const int* in_sizes, int n_in,
                              void* d_out, int out_size, void* d_ws, size_t ws_size,
                              hipStream_t stream) {
    const float* x_src = (const float*)d_in[0];
    const float* x_dst = (const float*)d_in[1];
    const float* Wv    = (const float*)d_in[2];
    const float* bv    = (const float*)d_in[3];
    const float* Wq    = (const float*)d_in[4];
    const float* bq    = (const float*)d_in[5];
    const float* Wk    = (const float*)d_in[6];
    const float* bk    = (const float*)d_in[7];
    const int* src_idx = (const int*)d_in[8];
    const int* dst_idx = (const int*)d_in[9];
    float* out = (float*)d_out;

    char* w = (char*)d_ws;
    unsigned short* Hx = (unsigned short*)w; w += (size_t)N_SRC_C * HPITCH * 2;  // 57.6 MB
    float* q  = (float*)w; w += (size_t)N_DST_C * HEADS_C * 4;                   // 3.2 MB
    int* off  = (int*)w;   w += 400128;                                          // (N+1)*4 rounded
    unsigned short* WTpad = (unsigned short*)w; w += (size_t)8 * B_ELEMS * 2;    // 174 KB
    float* baux16 = (float*)w; w += 256;

    k_prep<<<dim3(648), dim3(256), 0, stream>>>(Wv, bv, Wq, bq, Wk, bk, dst_idx,
                                                WTpad, baux16, off);
    k_gemm<<<dim3((M_TOT + BMg - 1) / BMg), dim3(512), 0, stream>>>(
        x_src, x_dst, WTpad, bv, baux16, Hx, q);
    k_gat_agg<<<dim3((N_DST_C + 3) / 4), dim3(256), 0, stream>>>(src_idx, off, q, Hx, out);
}

// Round 14
// 193.635 us; speedup vs baseline: 1.0306x; 1.0306x over previous
//
#include <hip/hip_runtime.h>
#include <hip/hip_bf16.h>
#include <stdint.h>

#define N_SRC_C 100000
#define N_DST_C 100000
#define M_TOT   200000
#define E_C     1600000
#define IN_FC   256
#define HEADS_C 8
#define OUT_FC  32
#define HF_C    256

// GEMM tile geometry
#define BMg 128
#define BKg 32
#define BPITCH 40                    // LDS row pitch in elems (32 + 8 pad, 80B = 2-way max)
#define A_ELEMS (BMg * BPITCH)       // 5120 elems / buffer
#define B_ROWS 272
#define B_ELEMS (B_ROWS * BPITCH)    // 10880 elems / buffer (21760 B)
#define B_CHUNKS 1360                // 21760 B / 16

typedef float f32x4_t __attribute__((ext_vector_type(4)));
typedef short s16x8_t __attribute__((ext_vector_type(8)));

static __device__ __forceinline__ unsigned short f2bf(float f) {
    union { __hip_bfloat16 h; unsigned short u; } cv;
    cv.h = __float2bfloat16(f);
    return cv.u;
}
static __device__ __forceinline__ float bf2f(unsigned short u) {
    return __uint_as_float(((unsigned int)u) << 16);
}

static __device__ __forceinline__ s16x8_t cvt8(f32x4_t x0, f32x4_t x1) {
    union { s16x8_t v; unsigned short u[8]; } r;
    r.u[0] = f2bf(x0[0]); r.u[1] = f2bf(x0[1]);
    r.u[2] = f2bf(x0[2]); r.u[3] = f2bf(x0[3]);
    r.u[4] = f2bf(x1[0]); r.u[5] = f2bf(x1[1]);
    r.u[6] = f2bf(x1[2]); r.u[7] = f2bf(x1[3]);
    return r.v;
}

// ---------------- K0: fused prep ----------------
__global__ __launch_bounds__(256) void k_prep(
    const float* __restrict__ Wv, const float* __restrict__ bv,
    const float* __restrict__ Wq, const float* __restrict__ bq,
    const float* __restrict__ Wk, const float* __restrict__ bk,
    const int* __restrict__ dst_idx,
    unsigned short* __restrict__ WTpad, float* __restrict__ baux16,
    int* __restrict__ off) {
    const int b = blockIdx.x;
    const int tid = threadIdx.x;
    __shared__ float sq[4][8], sk[4][8];
    if (b < 257) {
        const int i = b;
        float vv = (i < 256) ? Wv[(size_t)i * HF_C + tid] : bv[tid];
        f32x4_t q0 = *(const f32x4_t*)(Wq + tid * 8);
        f32x4_t q1 = *(const f32x4_t*)(Wq + tid * 8 + 4);
        f32x4_t k0 = *(const f32x4_t*)(Wk + tid * 8);
        f32x4_t k1 = *(const f32x4_t*)(Wk + tid * 8 + 4);
        float pq[8], pk[8];
#pragma unroll
        for (int h = 0; h < 4; ++h) {
            pq[h] = vv * q0[h]; pq[4 + h] = vv * q1[h];
            pk[h] = vv * k0[h]; pk[4 + h] = vv * k1[h];
        }
#pragma unroll
        for (int m = 1; m < 64; m <<= 1) {
#pragma unroll
            for (int h = 0; h < 8; ++h) {
                pq[h] += __shfl_xor(pq[h], m);
                pk[h] += __shfl_xor(pk[h], m);
            }
        }
        const int w = tid >> 6, ln = tid & 63;
        if (ln == 0) {
#pragma unroll
            for (int h = 0; h < 8; ++h) { sq[w][h] = pq[h]; sk[w][h] = pk[h]; }
        }
        __syncthreads();
        if (tid < 8) {
            float fq = sq[0][tid] + sq[1][tid] + sq[2][tid] + sq[3][tid];
            float fk = sk[0][tid] + sk[1][tid] + sk[2][tid] + sk[3][tid];
            if (i < 256) {
                WTpad[(i >> 5) * B_ELEMS + (256 + tid) * BPITCH + (i & 31)] = f2bf(fk);
                WTpad[(i >> 5) * B_ELEMS + (264 + tid) * BPITCH + (i & 31)] = f2bf(fq);
            } else {
                baux16[tid]     = fk + bk[tid];
                baux16[8 + tid] = fq + bq[tid];
            }
        }
        if (i < 256)
            WTpad[(tid >> 5) * B_ELEMS + i * BPITCH + (tid & 31)] =
                f2bf(Wv[(size_t)tid * HF_C + i]);
    } else {
        int n = (b - 257) * 256 + tid;
        if (n > N_DST_C) return;
        if (n == N_DST_C) { off[n] = E_C; return; }
        int lo = 0, hi = E_C;
        while (lo < hi) {
            int mid = (lo + hi) >> 1;
            if (dst_idx[mid] < n) lo = mid + 1; else hi = mid;
        }
        off[n] = lo;
    }
}

// ---------------- K1: pipelined merged GEMM over [x_src; x_dst] ----------------
// src rows -> H(bf16) + kkb(bf16, aux cols 0..7); dst rows -> q(f32, aux cols 8..15)
__global__ __launch_bounds__(512, 4) void k_gemm(
    const float* __restrict__ Xs, const float* __restrict__ Xd,
    const unsigned short* __restrict__ WTpad,
    const float* __restrict__ bmain, const float* __restrict__ baux16,
    unsigned short* __restrict__ H, unsigned short* __restrict__ kkb,
    float* __restrict__ qo) {
    __shared__ unsigned short smem[2 * A_ELEMS + 2 * B_ELEMS];   // 64,000 B
    unsigned short* As = smem;
    unsigned short* Bs = smem + 2 * A_ELEMS;
    const int tid  = threadIdx.x;
    const int lane = tid & 63;
    const int w    = tid >> 6;
    const int wr   = w >> 2, wc = w & 3;
    const int row0 = blockIdx.x * BMg;
    const bool need_main = (row0 < N_SRC_C);

    const int ar = tid >> 2, acg = tid & 3;
    int gr = row0 + ar; if (gr >= M_TOT) gr = M_TOT - 1;
    const float* arow = (gr < N_SRC_C) ? (Xs + (size_t)gr * IN_FC)
                                       : (Xd + (size_t)(gr - N_SRC_C) * IN_FC);

#define STAGE_B(kt, buf)                                                          \
    {                                                                             \
        const unsigned short* gsrc = WTpad + (size_t)(kt) * B_ELEMS;              \
        unsigned short* ldst = Bs + (buf) * B_ELEMS;                              \
        for (int g = w; g < 22; g += 8) {                                         \
            int c = g * 64 + lane;                                                \
            if (c < B_CHUNKS) {                                                   \
                __builtin_amdgcn_global_load_lds(                                 \
                    (const __attribute__((address_space(1))) unsigned int*)(gsrc + (size_t)c * 8), \
                    (__attribute__((address_space(3))) unsigned int*)(ldst + (size_t)c * 8),       \
                    16, 0, 0);                                                    \
            }                                                                     \
        }                                                                         \
    }

    f32x4_t acc[4][4];
    f32x4_t accA = {0.f, 0.f, 0.f, 0.f};
    const f32x4_t z = {0.f, 0.f, 0.f, 0.f};
#pragma unroll
    for (int m = 0; m < 4; ++m)
#pragma unroll
        for (int n = 0; n < 4; ++n) acc[m][n] = z;

    f32x4_t a0 = *(const f32x4_t*)(arow + acg * 8);
    f32x4_t a1 = *(const f32x4_t*)(arow + acg * 8 + 4);
    STAGE_B(0, 0);
    *(s16x8_t*)(As + ar * BPITCH + acg * 8) = cvt8(a0, a1);
    __syncthreads();
    a0 = *(const f32x4_t*)(arow + 32 + acg * 8);
    a1 = *(const f32x4_t*)(arow + 32 + acg * 8 + 4);
    STAGE_B(1, 1);

    const int koff = (lane >> 4) * 8;
    const int fr   = lane & 15;

    for (int kt = 0; kt < 8; ++kt) {
        const int cur = kt & 1;
        const unsigned short* Ab = As + cur * A_ELEMS;
        const unsigned short* Bb = Bs + cur * B_ELEMS;
        s16x8_t aa = *(const s16x8_t*)(Ab + (w * 16 + fr) * BPITCH + koff);
        s16x8_t ba = *(const s16x8_t*)(Bb + (256 + fr) * BPITCH + koff);
        accA = __builtin_amdgcn_mfma_f32_16x16x32_bf16(aa, ba, accA, 0, 0, 0);
        if (need_main) {
            s16x8_t a[4];
#pragma unroll
            for (int m = 0; m < 4; ++m)
                a[m] = *(const s16x8_t*)(Ab + (wr * 64 + m * 16 + fr) * BPITCH + koff);
#pragma unroll
            for (int n = 0; n < 4; ++n) {
                s16x8_t bf = *(const s16x8_t*)(Bb + (wc * 64 + n * 16 + fr) * BPITCH + koff);
#pragma unroll
                for (int m = 0; m < 4; ++m)
                    acc[m][n] = __builtin_amdgcn_mfma_f32_16x16x32_bf16(a[m], bf, acc[m][n], 0, 0, 0);
            }
        }
        if (kt < 7) {
            *(s16x8_t*)(As + (cur ^ 1) * A_ELEMS + ar * BPITCH + acg * 8) = cvt8(a0, a1);
            __syncthreads();
            if (kt < 6) {
                a0 = *(const f32x4_t*)(arow + (kt + 2) * 32 + acg * 8);
                a1 = *(const f32x4_t*)(arow + (kt + 2) * 32 + acg * 8 + 4);
                STAGE_B(kt + 2, cur);
            }
        }
    }

    // aux epilogue: kk bf16 (src rows, cols 0..7) / q f32 (dst rows, cols 8..15)
    {
        const int col0 = lane & 15;
        const float bb = baux16[col0];
        const int rb = row0 + w * 16 + (lane >> 4) * 4;
#pragma unroll
        for (int j = 0; j < 4; ++j) {
            int r = rb + j;
            float v = accA[j] + bb;
            if (r < N_SRC_C) {
                if (col0 < 8) kkb[(size_t)r * 8 + col0] = f2bf(v);
            } else if (r < M_TOT) {
                if (col0 >= 8) qo[(size_t)(r - N_SRC_C) * 8 + (col0 - 8)] = v;
            }
        }
    }

    // main epilogue: per-wave LDS repack (pitch 72, private region, no inner barriers)
    if (need_main) {
        __syncthreads();   // all frag reads done before reusing LDS
        unsigned short* reg = smem + w * 2304;   // 32 rows x 72
        float bb[4];
#pragma unroll
        for (int n = 0; n < 4; ++n) bb[n] = bmain[wc * 64 + n * 16 + fr];
#pragma unroll
        for (int g2 = 0; g2 < 2; ++g2) {
#pragma unroll
            for (int m2 = 0; m2 < 2; ++m2)
#pragma unroll
                for (int n = 0; n < 4; ++n)
#pragma unroll
                    for (int j = 0; j < 4; ++j) {
                        int lr = m2 * 16 + (lane >> 4) * 4 + j;
                        reg[lr * 72 + n * 16 + fr] = f2bf(acc[g2 * 2 + m2][n][j] + bb[n]);
                    }
#pragma unroll
            for (int i = 0; i < 4; ++i) {
                int lr = i * 8 + (lane >> 3);
                s16x8_t v = *(const s16x8_t*)(reg + lr * 72 + (lane & 7) * 8);
                int grr = row0 + wr * 64 + g2 * 32 + lr;
                if (grr < N_SRC_C)
                    *(s16x8_t*)(H + (size_t)grr * HF_C + wc * 64 + (lane & 7) * 8) = v;
            }
        }
    }
#undef STAGE_B
}

// ---------------- K2: fused weights (bf16 kv table) + aggregation (wave per dst) ----------------
// weight/den layout: lane = 8*e_sub + h_w   (8 edge-slots x 8 heads)
// gather layout:     lane = 32*ep + 4*hh + fc2  (2 edge-slots x 8 heads x 4 chunks of 8)
__global__ __launch_bounds__(256) void k_gat_agg(
    const int* __restrict__ src_idx, const int* __restrict__ off,
    const float* __restrict__ q, const unsigned short* __restrict__ kkb,
    const unsigned short* __restrict__ H, float* __restrict__ outp) {
    const int wv = (blockIdx.x * 256 + threadIdx.x) >> 6;
    const int lane = threadIdx.x & 63;
    if (wv >= N_DST_C) return;
    const int o0 = off[wv], o1 = off[wv + 1];
    const int e_sub = lane >> 3;
    const int h_w   = lane & 7;
    const int hh    = (lane >> 2) & 7;
    const int fc2   = lane & 3;
    const int selA  = ((lane >> 5) << 3) | hh;   // 8*ep + hh
    if (o1 <= o0) {
        if (lane < 4) {
            f32x4_t zv = {0.f, 0.f, 0.f, 0.f};
            *(f32x4_t*)(outp + (size_t)wv * 32 + lane * 8) = zv;
            *(f32x4_t*)(outp + (size_t)wv * 32 + lane * 8 + 4) = zv;
        }
        return;
    }
    const int last = o1 - 1;
    const float q_w = q[(size_t)wv * 8 + h_w];
    float den_w = 0.f;
    float a[8];
#pragma unroll
    for (int i = 0; i < 8; ++i) a[i] = 0.f;
    const unsigned short* Hb = H + hh * 32 + fc2 * 8;

    int s0 = src_idx[min(o0 + e_sub, last)];
    int s1 = src_idx[min(o0 + 8 + e_sub, last)];

    for (int base = o0; base < o1; base += 16) {
        // 1) kv loads first (small, critical path for weights)
        const float kv0 = bf2f(kkb[(size_t)s0 * 8 + h_w]);
        const float kv1 = bf2f(kkb[(size_t)s1 * 8 + h_w]);
        // 2) issue all 8 row-gathers (depend only on s0/s1)
        uint4 xv[8];
#pragma unroll
        for (int j = 0; j < 4; ++j) {
            const int se = __shfl(s0, j * 16 + selA);
            xv[j] = *(const uint4*)(Hb + (size_t)se * 256);
        }
#pragma unroll
        for (int j = 0; j < 4; ++j) {
            const int se = __shfl(s1, j * 16 + selA);
            xv[4 + j] = *(const uint4*)(Hb + (size_t)se * 256);
        }
        // 3) prefetch next tile indices
        const int sn0 = src_idx[min(base + 16 + e_sub, last)];
        const int sn1 = src_idx[min(base + 24 + e_sub, last)];
        float ev0 = q_w + kv0; ev0 = (ev0 >= 0.f) ? ev0 : 0.2f * ev0;
        float ev1 = q_w + kv1; ev1 = (ev1 >= 0.f) ? ev1 : 0.2f * ev1;
        const float p0 = (base + e_sub < o1) ? __expf(ev0) : 0.f;
        const float p1 = (base + 8 + e_sub < o1) ? __expf(ev1) : 0.f;
        den_w += p0 + p1;
#pragma unroll
        for (int j = 0; j < 8; ++j) {
            const float wgt = __shfl(j < 4 ? p0 : p1, (j & 3) * 16 + selA);
            a[0] += wgt * __uint_as_float(xv[j].x << 16);
            a[1] += wgt * __uint_as_float(xv[j].x & 0xffff0000u);
            a[2] += wgt * __uint_as_float(xv[j].y << 16);
            a[3] += wgt * __uint_as_float(xv[j].y & 0xffff0000u);
            a[4] += wgt * __uint_as_float(xv[j].z << 16);
            a[5] += wgt * __uint_as_float(xv[j].z & 0xffff0000u);
            a[6] += wgt * __uint_as_float(xv[j].w << 16);
            a[7] += wgt * __uint_as_float(xv[j].w & 0xffff0000u);
        }
        s0 = sn0; s1 = sn1;
    }
    // denominator: reduce over edge-slot lanes (weight layout)
    den_w += __shfl_xor(den_w, 8);
    den_w += __shfl_xor(den_w, 16);
    den_w += __shfl_xor(den_w, 32);
    const float rs_w = 1.f / (den_w + 1e-9f);
    const float rs_a = __shfl(rs_w, hh) * 0.125f;   // per-head norm + /8 head-mean
#pragma unroll
    for (int i = 0; i < 8; ++i) {
        a[i] += __shfl_xor(a[i], 32);   // sum the two edge-slot halves
        a[i] *= rs_a;
        a[i] += __shfl_xor(a[i], 4);    // sum over heads (bits 2..4)
        a[i] += __shfl_xor(a[i], 8);
        a[i] += __shfl_xor(a[i], 16);
    }
    if (lane < 4) {
        f32x4_t v0 = {a[0], a[1], a[2], a[3]};
        f32x4_t v1 = {a[4], a[5], a[6], a[7]};
        *(f32x4_t*)(outp + (size_t)wv * 32 + lane * 8) = v0;
        *(f32x4_t*)(outp + (size_t)wv * 32 + lane * 8 + 4) = v1;
    }
}

extern "C" void kernel_launch(void* const* d_in, const int* in_sizes, int n_in,
                              void* d_out, int out_size, void* d_ws, size_t ws_size,
                              hipStream_t stream) {
    const float* x_src = (const float*)d_in[0];
    const float* x_dst = (const float*)d_in[1];
    const float* Wv    = (const float*)d_in[2];
    const float* bv    = (const float*)d_in[3];
    const float* Wq    = (const float*)d_in[4];
    const float* bq    = (const float*)d_in[5];
    const float* Wk    = (const float*)d_in[6];
    const float* bk    = (const float*)d_in[7];
    const int* src_idx = (const int*)d_in[8];
    const int* dst_idx = (const int*)d_in[9];
    float* out = (float*)d_out;

    char* w = (char*)d_ws;
    unsigned short* H = (unsigned short*)w; w += (size_t)N_SRC_C * HF_C * 2;   // 51.2 MB
    float* q  = (float*)w; w += (size_t)N_DST_C * HEADS_C * 4;                 // 3.2 MB
    unsigned short* kkb = (unsigned short*)w; w += (size_t)N_SRC_C * HEADS_C * 2; // 1.6 MB
    int* off  = (int*)w;   w += 400128;                                        // (N+1)*4 rounded
    unsigned short* WTpad = (unsigned short*)w; w += (size_t)8 * B_ELEMS * 2;  // 174 KB
    float* baux16 = (float*)w; w += 256;

    k_prep<<<dim3(648), dim3(256), 0, stream>>>(Wv, bv, Wq, bq, Wk, bk, dst_idx,
                                                WTpad, baux16, off);
    k_gemm<<<dim3((M_TOT + BMg - 1) / BMg), dim3(512), 0, stream>>>(
        x_src, x_dst, WTpad, bv, baux16, H, kkb, q);
    k_gat_agg<<<dim3((N_DST_C + 3) / 4), dim3(256), 0, stream>>>(src_idx, off, q, kkb, H, out);
}

// Round 15
// 190.571 us; speedup vs baseline: 1.0472x; 1.0161x over previous
//
#include <hip/hip_runtime.h>
#include <hip/hip_bf16.h>
#include <stdint.h>

#define N_SRC_C 100000
#define N_DST_C 100000
#define M_TOT   200000
#define E_C     1600000
#define IN_FC   256
#define HEADS_C 8
#define OUT_FC  32
#define HF_C    256

// GEMM tile geometry
#define BMg 128
#define BKg 32
#define BPITCH 40                    // LDS row pitch in elems (32 + 8 pad, 80B = 2-way max)
#define A_ELEMS (BMg * BPITCH)       // 5120 elems / buffer
#define B_ROWS 272
#define B_ELEMS (B_ROWS * BPITCH)    // 10880 elems / buffer (21760 B)
#define B_CHUNKS 1360                // 21760 B / 16

typedef float f32x4_t __attribute__((ext_vector_type(4)));
typedef short s16x8_t __attribute__((ext_vector_type(8)));

static __device__ __forceinline__ unsigned short f2bf(float f) {
    union { __hip_bfloat16 h; unsigned short u; } cv;
    cv.h = __float2bfloat16(f);
    return cv.u;
}
static __device__ __forceinline__ float bf2f(unsigned short u) {
    return __uint_as_float(((unsigned int)u) << 16);
}

static __device__ __forceinline__ s16x8_t cvt8(f32x4_t x0, f32x4_t x1) {
    union { s16x8_t v; unsigned short u[8]; } r;
    r.u[0] = f2bf(x0[0]); r.u[1] = f2bf(x0[1]);
    r.u[2] = f2bf(x0[2]); r.u[3] = f2bf(x0[3]);
    r.u[4] = f2bf(x1[0]); r.u[5] = f2bf(x1[1]);
    r.u[6] = f2bf(x1[2]); r.u[7] = f2bf(x1[3]);
    return r.v;
}

// ---------------- K0: fused prep ----------------
__global__ __launch_bounds__(256) void k_prep(
    const float* __restrict__ Wv, const float* __restrict__ bv,
    const float* __restrict__ Wq, const float* __restrict__ bq,
    const float* __restrict__ Wk, const float* __restrict__ bk,
    const int* __restrict__ dst_idx,
    unsigned short* __restrict__ WTpad, float* __restrict__ baux16,
    int* __restrict__ off) {
    const int b = blockIdx.x;
    const int tid = threadIdx.x;
    __shared__ float sq[4][8], sk[4][8];
    if (b < 257) {
        const int i = b;
        float vv = (i < 256) ? Wv[(size_t)i * HF_C + tid] : bv[tid];
        f32x4_t q0 = *(const f32x4_t*)(Wq + tid * 8);
        f32x4_t q1 = *(const f32x4_t*)(Wq + tid * 8 + 4);
        f32x4_t k0 = *(const f32x4_t*)(Wk + tid * 8);
        f32x4_t k1 = *(const f32x4_t*)(Wk + tid * 8 + 4);
        float pq[8], pk[8];
#pragma unroll
        for (int h = 0; h < 4; ++h) {
            pq[h] = vv * q0[h]; pq[4 + h] = vv * q1[h];
            pk[h] = vv * k0[h]; pk[4 + h] = vv * k1[h];
        }
#pragma unroll
        for (int m = 1; m < 64; m <<= 1) {
#pragma unroll
            for (int h = 0; h < 8; ++h) {
                pq[h] += __shfl_xor(pq[h], m);
                pk[h] += __shfl_xor(pk[h], m);
            }
        }
        const int w = tid >> 6, ln = tid & 63;
        if (ln == 0) {
#pragma unroll
            for (int h = 0; h < 8; ++h) { sq[w][h] = pq[h]; sk[w][h] = pk[h]; }
        }
        __syncthreads();
        if (tid < 8) {
            float fq = sq[0][tid] + sq[1][tid] + sq[2][tid] + sq[3][tid];
            float fk = sk[0][tid] + sk[1][tid] + sk[2][tid] + sk[3][tid];
            if (i < 256) {
                WTpad[(i >> 5) * B_ELEMS + (256 + tid) * BPITCH + (i & 31)] = f2bf(fk);
                WTpad[(i >> 5) * B_ELEMS + (264 + tid) * BPITCH + (i & 31)] = f2bf(fq);
            } else {
                baux16[tid]     = fk + bk[tid];
                baux16[8 + tid] = fq + bq[tid];
            }
        }
        if (i < 256)
            WTpad[(tid >> 5) * B_ELEMS + i * BPITCH + (tid & 31)] =
                f2bf(Wv[(size_t)tid * HF_C + i]);
    } else {
        int n = (b - 257) * 256 + tid;
        if (n > N_DST_C) return;
        if (n == N_DST_C) { off[n] = E_C; return; }
        int lo = 0, hi = E_C;
        while (lo < hi) {
            int mid = (lo + hi) >> 1;
            if (dst_idx[mid] < n) lo = mid + 1; else hi = mid;
        }
        off[n] = lo;
    }
}

// ---------------- K1: pipelined merged GEMM over [x_src; x_dst] ----------------
// src rows -> H(bf16) + kkb(bf16, aux cols 0..7); dst rows -> q(f32, aux cols 8..15)
__global__ __launch_bounds__(512, 4) void k_gemm(
    const float* __restrict__ Xs, const float* __restrict__ Xd,
    const unsigned short* __restrict__ WTpad,
    const float* __restrict__ bmain, const float* __restrict__ baux16,
    unsigned short* __restrict__ H, unsigned short* __restrict__ kkb,
    float* __restrict__ qo) {
    __shared__ unsigned short smem[2 * A_ELEMS + 2 * B_ELEMS];   // 64,000 B
    unsigned short* As = smem;
    unsigned short* Bs = smem + 2 * A_ELEMS;
    const int tid  = threadIdx.x;
    const int lane = tid & 63;
    const int w    = tid >> 6;
    const int wr   = w >> 2, wc = w & 3;
    const int row0 = blockIdx.x * BMg;
    const bool need_main = (row0 < N_SRC_C);

    const int ar = tid >> 2, acg = tid & 3;
    int gr = row0 + ar; if (gr >= M_TOT) gr = M_TOT - 1;
    const float* arow = (gr < N_SRC_C) ? (Xs + (size_t)gr * IN_FC)
                                       : (Xd + (size_t)(gr - N_SRC_C) * IN_FC);

#define STAGE_B(kt, buf)                                                          \
    {                                                                             \
        const unsigned short* gsrc = WTpad + (size_t)(kt) * B_ELEMS;              \
        unsigned short* ldst = Bs + (buf) * B_ELEMS;                              \
        for (int g = w; g < 22; g += 8) {                                         \
            int c = g * 64 + lane;                                                \
            if (c < B_CHUNKS) {                                                   \
                __builtin_amdgcn_global_load_lds(                                 \
                    (const __attribute__((address_space(1))) unsigned int*)(gsrc + (size_t)c * 8), \
                    (__attribute__((address_space(3))) unsigned int*)(ldst + (size_t)c * 8),       \
                    16, 0, 0);                                                    \
            }                                                                     \
        }                                                                         \
    }

    f32x4_t acc[4][4];
    f32x4_t accA = {0.f, 0.f, 0.f, 0.f};
    const f32x4_t z = {0.f, 0.f, 0.f, 0.f};
#pragma unroll
    for (int m = 0; m < 4; ++m)
#pragma unroll
        for (int n = 0; n < 4; ++n) acc[m][n] = z;

    f32x4_t a0 = *(const f32x4_t*)(arow + acg * 8);
    f32x4_t a1 = *(const f32x4_t*)(arow + acg * 8 + 4);
    STAGE_B(0, 0);
    *(s16x8_t*)(As + ar * BPITCH + acg * 8) = cvt8(a0, a1);
    __syncthreads();
    a0 = *(const f32x4_t*)(arow + 32 + acg * 8);
    a1 = *(const f32x4_t*)(arow + 32 + acg * 8 + 4);
    STAGE_B(1, 1);

    const int koff = (lane >> 4) * 8;
    const int fr   = lane & 15;

    for (int kt = 0; kt < 8; ++kt) {
        const int cur = kt & 1;
        const unsigned short* Ab = As + cur * A_ELEMS;
        const unsigned short* Bb = Bs + cur * B_ELEMS;
        s16x8_t aa = *(const s16x8_t*)(Ab + (w * 16 + fr) * BPITCH + koff);
        s16x8_t ba = *(const s16x8_t*)(Bb + (256 + fr) * BPITCH + koff);
        accA = __builtin_amdgcn_mfma_f32_16x16x32_bf16(aa, ba, accA, 0, 0, 0);
        if (need_main) {
            s16x8_t a[4];
#pragma unroll
            for (int m = 0; m < 4; ++m)
                a[m] = *(const s16x8_t*)(Ab + (wr * 64 + m * 16 + fr) * BPITCH + koff);
#pragma unroll
            for (int n = 0; n < 4; ++n) {
                s16x8_t bf = *(const s16x8_t*)(Bb + (wc * 64 + n * 16 + fr) * BPITCH + koff);
#pragma unroll
                for (int m = 0; m < 4; ++m)
                    acc[m][n] = __builtin_amdgcn_mfma_f32_16x16x32_bf16(a[m], bf, acc[m][n], 0, 0, 0);
            }
        }
        if (kt < 7) {
            *(s16x8_t*)(As + (cur ^ 1) * A_ELEMS + ar * BPITCH + acg * 8) = cvt8(a0, a1);
            __syncthreads();
            if (kt < 6) {
                a0 = *(const f32x4_t*)(arow + (kt + 2) * 32 + acg * 8);
                a1 = *(const f32x4_t*)(arow + (kt + 2) * 32 + acg * 8 + 4);
                STAGE_B(kt + 2, cur);
            }
        }
    }

    // aux epilogue: kk bf16 (src rows, cols 0..7) / q f32 (dst rows, cols 8..15)
    {
        const int col0 = lane & 15;
        const float bb = baux16[col0];
        const int rb = row0 + w * 16 + (lane >> 4) * 4;
#pragma unroll
        for (int j = 0; j < 4; ++j) {
            int r = rb + j;
            float v = accA[j] + bb;
            if (r < N_SRC_C) {
                if (col0 < 8) kkb[(size_t)r * 8 + col0] = f2bf(v);
            } else if (r < M_TOT) {
                if (col0 >= 8) qo[(size_t)(r - N_SRC_C) * 8 + (col0 - 8)] = v;
            }
        }
    }

    // main epilogue: per-wave LDS repack (pitch 72, private region, no inner barriers)
    if (need_main) {
        __syncthreads();   // all frag reads done before reusing LDS
        unsigned short* reg = smem + w * 2304;   // 32 rows x 72
        float bb[4];
#pragma unroll
        for (int n = 0; n < 4; ++n) bb[n] = bmain[wc * 64 + n * 16 + fr];
#pragma unroll
        for (int g2 = 0; g2 < 2; ++g2) {
#pragma unroll
            for (int m2 = 0; m2 < 2; ++m2)
#pragma unroll
                for (int n = 0; n < 4; ++n)
#pragma unroll
                    for (int j = 0; j < 4; ++j) {
                        int lr = m2 * 16 + (lane >> 4) * 4 + j;
                        reg[lr * 72 + n * 16 + fr] = f2bf(acc[g2 * 2 + m2][n][j] + bb[n]);
                    }
#pragma unroll
            for (int i = 0; i < 4; ++i) {
                int lr = i * 8 + (lane >> 3);
                s16x8_t v = *(const s16x8_t*)(reg + lr * 72 + (lane & 7) * 8);
                int grr = row0 + wr * 64 + g2 * 32 + lr;
                if (grr < N_SRC_C)
                    *(s16x8_t*)(H + (size_t)grr * HF_C + wc * 64 + (lane & 7) * 8) = v;
            }
        }
    }
#undef STAGE_B
}

// ---------------- K2: fused weights (bf16 kv table) + aggregation (wave per dst) ----------------
// weight/den layout: lane = 8*e_sub + h_w   (8 edge-slots x 8 heads)
// gather layout:     lane = 32*ep + 4*hh + fc2  (2 edge-slots x 8 heads x 4 chunks of 8)
__global__ __launch_bounds__(256) void k_gat_agg(
    const int* __restrict__ src_idx, const int* __restrict__ off,
    const float* __restrict__ q, const unsigned short* __restrict__ kkb,
    const unsigned short* __restrict__ H, float* __restrict__ outp) {
    const int wv = (blockIdx.x * 256 + threadIdx.x) >> 6;
    const int lane = threadIdx.x & 63;
    if (wv >= N_DST_C) return;
    const int o0 = off[wv], o1 = off[wv + 1];
    const int e_sub = lane >> 3;
    const int h_w   = lane & 7;
    const int hh    = (lane >> 2) & 7;
    const int fc2   = lane & 3;
    const int selA  = ((lane >> 5) << 3) | hh;   // 8*ep + hh
    if (o1 <= o0) {
        if (lane < 4) {
            f32x4_t zv = {0.f, 0.f, 0.f, 0.f};
            *(f32x4_t*)(outp + (size_t)wv * 32 + lane * 8) = zv;
            *(f32x4_t*)(outp + (size_t)wv * 32 + lane * 8 + 4) = zv;
        }
        return;
    }
    const int last = o1 - 1;
    const float q_w = q[(size_t)wv * 8 + h_w];
    float den_w = 0.f;
    float a[8];
#pragma unroll
    for (int i = 0; i < 8; ++i) a[i] = 0.f;
    const unsigned short* Hb = H + hh * 32 + fc2 * 8;

    int s0 = src_idx[min(o0 + e_sub, last)];
    int s1 = src_idx[min(o0 + 8 + e_sub, last)];

    for (int base = o0; base < o1; base += 16) {
        // 1) issue all 8 row-gathers (depend only on s0/s1)
        uint4 xv[8];
#pragma unroll
        for (int j = 0; j < 4; ++j) {
            const int se = __shfl(s0, j * 16 + selA);
            xv[j] = *(const uint4*)(Hb + (size_t)se * 256);
        }
#pragma unroll
        for (int j = 0; j < 4; ++j) {
            const int se = __shfl(s1, j * 16 + selA);
            xv[4 + j] = *(const uint4*)(Hb + (size_t)se * 256);
        }
        // 2) weights inline (bf16 kv table, 1.6 MB -> L2-resident) under gather latency
        const float kv0 = bf2f(kkb[(size_t)s0 * 8 + h_w]);
        const float kv1 = bf2f(kkb[(size_t)s1 * 8 + h_w]);
        // 3) prefetch next tile indices
        const int sn0 = src_idx[min(base + 16 + e_sub, last)];
        const int sn1 = src_idx[min(base + 24 + e_sub, last)];
        float ev0 = q_w + kv0; ev0 = (ev0 >= 0.f) ? ev0 : 0.2f * ev0;
        float ev1 = q_w + kv1; ev1 = (ev1 >= 0.f) ? ev1 : 0.2f * ev1;
        const float p0 = (base + e_sub < o1) ? __expf(ev0) : 0.f;
        const float p1 = (base + 8 + e_sub < o1) ? __expf(ev1) : 0.f;
        den_w += p0 + p1;
#pragma unroll
        for (int j = 0; j < 8; ++j) {
            const float wgt = __shfl(j < 4 ? p0 : p1, (j & 3) * 16 + selA);
            a[0] += wgt * __uint_as_float(xv[j].x << 16);
            a[1] += wgt * __uint_as_float(xv[j].x & 0xffff0000u);
            a[2] += wgt * __uint_as_float(xv[j].y << 16);
            a[3] += wgt * __uint_as_float(xv[j].y & 0xffff0000u);
            a[4] += wgt * __uint_as_float(xv[j].z << 16);
            a[5] += wgt * __uint_as_float(xv[j].z & 0xffff0000u);
            a[6] += wgt * __uint_as_float(xv[j].w << 16);
            a[7] += wgt * __uint_as_float(xv[j].w & 0xffff0000u);
        }
        s0 = sn0; s1 = sn1;
    }
    // denominator: reduce over edge-slot lanes (weight layout)
    den_w += __shfl_xor(den_w, 8);
    den_w += __shfl_xor(den_w, 16);
    den_w += __shfl_xor(den_w, 32);
    const float rs_w = 1.f / (den_w + 1e-9f);
    const float rs_a = __shfl(rs_w, hh) * 0.125f;   // per-head norm + /8 head-mean
#pragma unroll
    for (int i = 0; i < 8; ++i) {
        a[i] += __shfl_xor(a[i], 32);   // sum the two edge-slot halves
        a[i] *= rs_a;
        a[i] += __shfl_xor(a[i], 4);    // sum over heads (bits 2..4)
        a[i] += __shfl_xor(a[i], 8);
        a[i] += __shfl_xor(a[i], 16);
    }
    if (lane < 4) {
        f32x4_t v0 = {a[0], a[1], a[2], a[3]};
        f32x4_t v1 = {a[4], a[5], a[6], a[7]};
        *(f32x4_t*)(outp + (size_t)wv * 32 + lane * 8) = v0;
        *(f32x4_t*)(outp + (size_t)wv * 32 + lane * 8 + 4) = v1;
    }
}

extern "C" void kernel_launch(void* const* d_in, const int* in_sizes, int n_in,
                              void* d_out, int out_size, void* d_ws, size_t ws_size,
                              hipStream_t stream) {
    const float* x_src = (const float*)d_in[0];
    const float* x_dst = (const float*)d_in[1];
    const float* Wv    = (const float*)d_in[2];
    const float* bv    = (const float*)d_in[3];
    const float* Wq    = (const float*)d_in[4];
    const float* bq    = (const float*)d_in[5];
    const float* Wk    = (const float*)d_in[6];
    const float* bk    = (const float*)d_in[7];
    const int* src_idx = (const int*)d_in[8];
    const int* dst_idx = (const int*)d_in[9];
    float* out = (float*)d_out;

    char* w = (char*)d_ws;
    unsigned short* H = (unsigned short*)w; w += (size_t)N_SRC_C * HF_C * 2;   // 51.2 MB
    float* q  = (float*)w; w += (size_t)N_DST_C * HEADS_C * 4;                 // 3.2 MB
    unsigned short* kkb = (unsigned short*)w; w += (size_t)N_SRC_C * HEADS_C * 2; // 1.6 MB
    int* off  = (int*)w;   w += 400128;                                        // (N+1)*4 rounded
    unsigned short* WTpad = (unsigned short*)w; w += (size_t)8 * B_ELEMS * 2;  // 174 KB
    float* baux16 = (float*)w; w += 256;

    k_prep<<<dim3(648), dim3(256), 0, stream>>>(Wv, bv, Wq, bq, Wk, bk, dst_idx,
                                                WTpad, baux16, off);
    k_gemm<<<dim3((M_TOT + BMg - 1) / BMg), dim3(512), 0, stream>>>(
        x_src, x_dst, WTpad, bv, baux16, H, kkb, q);
    k_gat_agg<<<dim3((N_DST_C + 3) / 4), dim3(256), 0, stream>>>(src_idx, off, q, kkb, H, out);
}